// Round 1
// baseline (1370.390 us; speedup 1.0000x reference)
//
#include <hip/hip_runtime.h>

#define NBS 256

// ws layout (float offsets)
#define LT0_OFF 0         // 16*50*64   = 51200
#define LT1_OFF 51200     // 16*100*112 = 179200
#define LT2_OFF 230400    // 16*150*160 = 384000
#define A0_OFF  614400    // 16*64*2  = 2048
#define A1_OFF  616448    // 16*112*2 = 3584
#define A2_OFF  620032    // 16*160*2 = 5120
#define PART_OFF 625152   // 48 partial ldj sums

__device__ __forceinline__ int tri_i(int p) { return (p * (p + 1)) >> 1; }

// ---------------------------------------------------------------------------
// Kernel A: per (j,d) build A_mu, Sigma, Cholesky (raw Schur form, 1 barrier/k),
// write L^T (zero-padded to MP cols) + A_mu (padded) + partial ldj to ws.
// ---------------------------------------------------------------------------
__global__ __launch_bounds__(256) void build_kernel(const float* __restrict__ ts,
                                                    const float* __restrict__ log_tau,
                                                    float* __restrict__ ws)
{
  __shared__ float sS[11325];   // packed lower triangle, max m=150
  __shared__ float stj[152];
  __shared__ float sAmu[320];
  __shared__ float sKp[304];
  __shared__ float red[256];

  const int j = blockIdx.x >> 4;
  const int d = blockIdx.x & 15;
  const int m = (j + 1) * 50;
  const int mp    = (j == 0) ? 64      : ((j == 1) ? 112     : 160);
  const int ltoff = (j == 0) ? LT0_OFF : ((j == 1) ? LT1_OFF : LT2_OFF);
  const int aoff  = (j == 0) ? A0_OFF  : ((j == 1) ? A1_OFF  : A2_OFF);
  const float tpsj = (j == 0) ? 10.0f : ((j == 1) ? 20.0f : 30.0f);
  const int tid = threadIdx.x;

  const float tau = expf(log_tau[d]);
  const float cc = 1.0f / (2.0f * tau * tau);

  for (int i = tid; i < m; i += NBS) stj[i] = ts[i];
  __syncthreads();

  // 2x2 K_EPEP inverse: K = [[1,k01],[k01,1]]
  const float k01 = expf(-tpsj * tpsj * cc);
  const float det = 1.0f - k01 * k01;
  const float i00 = 1.0f / det;
  const float i01 = -k01 / det;

  for (int p = tid; p < m; p += NBS) {
    float tp = stj[p];
    float kp0 = expf(-tp * tp * cc);          // vs t=0
    float dt = tp - tpsj;
    float kp1 = expf(-dt * dt * cc);          // vs t=TPS[j]
    sKp[p * 2 + 0] = kp0; sKp[p * 2 + 1] = kp1;
    sAmu[p * 2 + 0] = fmaf(kp0, i00, kp1 * i01);
    sAmu[p * 2 + 1] = fmaf(kp0, i01, kp1 * i00);
  }
  __syncthreads();

  // Sigma (packed lower triangle)
  const int tot = tri_i(m);
  for (int e = tid; e < tot; e += NBS) {
    int r = (int)((sqrtf(8.0f * (float)e + 1.0f) - 1.0f) * 0.5f);
    while (tri_i(r + 1) <= e) ++r;
    while (r > 0 && tri_i(r) > e) --r;
    int q = e - tri_i(r);
    float dq = stj[r] - stj[q];
    float v = expf(-dq * dq * cc)
            - fmaf(sAmu[r * 2], sKp[q * 2], sAmu[r * 2 + 1] * sKp[q * 2 + 1]);
    if (r == q) v += 1e-4f;
    sS[e] = v;
  }
  __syncthreads();

  // Raw Schur-complement Cholesky: columns stay UNSCALED; diag holds d_k = L_kk^2.
  // Only writes touch (i,q) with i,q > k, reads touch column k / diag k -> 1 barrier/k.
  for (int k = 0; k < m - 1; ++k) {
    const float skk = sS[tri_i(k) + k];
    const float inv = 1.0f / skk;
    const int n = m - 1 - k;
    const int tt = (n * (n + 1)) >> 1;
    for (int e = tid; e < tt; e += NBS) {
      int r = (int)((sqrtf(8.0f * (float)e + 1.0f) - 1.0f) * 0.5f);
      while (tri_i(r + 1) <= e) ++r;
      while (r > 0 && tri_i(r) > e) --r;
      int c = e - tri_i(r);
      int i = k + 1 + r;
      int q = k + 1 + c;
      float ci = sS[tri_i(i) + k];
      float cq = sS[tri_i(q) + k];
      sS[tri_i(i) + q] = fmaf(-(ci * inv), cq, sS[tri_i(i) + q]);
    }
    __syncthreads();
  }

  // ldj partial: sum 0.5*log(d_p)
  float part = 0.0f;
  for (int p = tid; p < m; p += NBS) part += 0.5f * logf(sS[tri_i(p) + p]);
  red[tid] = part;
  __syncthreads();
  for (int s = 128; s > 0; s >>= 1) {
    if (tid < s) red[tid] += red[tid + s];
    __syncthreads();
  }
  if (tid == 0) ws[PART_OFF + blockIdx.x] = red[0];

  // L^T write, zero-padded: LT[q][p] = L[p][q] = S[p][q]/sqrt(d_q) (p>q), sqrt(d_p) (p==q)
  float* LTg = ws + ltoff + d * (m * mp);
  for (int idx = tid; idx < m * mp; idx += NBS) {
    int q = idx / mp;
    int p = idx - q * mp;
    float v = 0.0f;
    if (p < m && p >= q) {
      float dq = sS[tri_i(q) + q];
      v = (p == q) ? sqrtf(dq) : sS[tri_i(p) + q] * rsqrtf(dq);
    }
    LTg[idx] = v;
  }
  // A_mu write, zero-padded to mp rows
  float* Ag = ws + aoff + d * (mp * 2);
  for (int idx = tid; idx < mp * 2; idx += NBS) {
    int p = idx >> 1;
    Ag[idx] = (p < m) ? sAmu[idx] : 0.0f;
  }
}

// ---------------------------------------------------------------------------
// Kernel B: z_hat = A_mu * z_EP + L * z_mid, 64 rows/block, lane=row,
// waves own p-groups of 16, L rows are wave-uniform scalar loads.
// ---------------------------------------------------------------------------
template <int M, int MP, int TOFF, int OOFF, int LTOFF, int AOFF>
__device__ __forceinline__ void apply_impl(const float* __restrict__ z,
                                           const float* __restrict__ ws,
                                           float* __restrict__ out,
                                           float* zsh, int blk)
{
  constexpr int W = M + 3;            // odd row stride -> conflict-free columns
  constexpr int G = MP / 16;          // p-groups
  constexpr int NGW = (G + 3) / 4;    // max groups per wave
  const int d = blk & 15;
  const int bs0 = (blk >> 4) * 64;
  const int tid = threadIdx.x;
  const int lane = tid & 63;
  const int w = __builtin_amdgcn_readfirstlane(tid >> 6);

  // stage rows: [zf, zl, z_mid(0..M-1)]
  const float* zbase = z + (size_t)(bs0 * 16 + d) * 302;
  for (int idx = tid; idx < 64 * (M + 2); idx += NBS) {
    int rr = idx / (M + 2);
    int c = idx - rr * (M + 2);
    int t = (c < 2) ? c : (TOFF + c - 2);
    zsh[rr * W + c] = zbase[(size_t)rr * 4832 + t];
  }
  __syncthreads();

  float acc[NGW][16];
  const float* Ad = ws + AOFF + d * (MP * 2);
  const float* Ld = ws + LTOFF + d * (M * MP);
  const float zf = zsh[lane * W + 0];
  const float zl = zsh[lane * W + 1];

#pragma unroll
  for (int gi = 0; gi < NGW; ++gi) {
    const int g = w + 4 * gi;
    if (g < G) {
      const int pbase = g * 16;
#pragma unroll
      for (int i = 0; i < 16; ++i)
        acc[gi][i] = fmaf(Ad[(pbase + i) * 2 + 0], zf, Ad[(pbase + i) * 2 + 1] * zl);
      const float* Lp = Ld + pbase;
      for (int q = 0; q < M; ++q) {
        const float zv = zsh[lane * W + 2 + q];
        const float* Lr = Lp + q * MP;   // wave-uniform -> s_load
#pragma unroll
        for (int i = 0; i < 16; ++i)
          acc[gi][i] = fmaf(Lr[i], zv, acc[gi][i]);
      }
    }
  }
  __syncthreads();

  // write z_hat back into the LDS tile (cols 2..M+1); zf/zl at cols 0,1 preserved
#pragma unroll
  for (int gi = 0; gi < NGW; ++gi) {
    const int g = w + 4 * gi;
    if (g < G) {
      const int pbase = g * 16;
#pragma unroll
      for (int i = 0; i < 16; ++i) {
        const int p = pbase + i;
        if (p < M) zsh[lane * W + 2 + p] = acc[gi][i];
      }
    }
  }
  __syncthreads();

  // coalesced store: out row segment = [zf, z_hat(0..M-1), zl]
  for (int idx = tid; idx < 64 * (M + 2); idx += NBS) {
    int rr = idx / (M + 2);
    int c = idx - rr * (M + 2);
    float v = (c == 0) ? zsh[rr * W]
            : ((c == M + 1) ? zsh[rr * W + 1] : zsh[rr * W + c + 1]);
    out[(size_t)((bs0 + rr) * 16 + d) * 306 + OOFF + c] = v;
  }
}

__global__ __launch_bounds__(256) void apply_kernel(const float* __restrict__ z,
                                                    const float* __restrict__ ws,
                                                    float* __restrict__ out)
{
  __shared__ float zsh[64 * 153];
  const int bid = blockIdx.x;
  if (bid < 512)       apply_impl<150, 160, 152, 154, LT2_OFF, A2_OFF>(z, ws, out, zsh, bid);
  else if (bid < 1024) apply_impl<100, 112,  52,  52, LT1_OFF, A1_OFF>(z, ws, out, zsh, bid - 512);
  else                 apply_impl< 50,  64,   2,   0, LT0_OFF, A0_OFF>(z, ws, out, zsh, bid - 1024);
}

// ---------------------------------------------------------------------------
// Kernel C: ldj = sldj_in + sum of 48 partials
// ---------------------------------------------------------------------------
__global__ void finalize_kernel(const float* __restrict__ ws_part,
                                const float* __restrict__ sldj,
                                float* __restrict__ out, int last)
{
  if (threadIdx.x == 0) {
    float s = sldj[0];
    for (int i = 0; i < 48; ++i) s += ws_part[i];
    out[last] = s;
  }
}

extern "C" void kernel_launch(void* const* d_in, const int* in_sizes, int n_in,
                              void* d_out, int out_size, void* d_ws, size_t ws_size,
                              hipStream_t stream)
{
  const float* z       = (const float*)d_in[0];  // (16,128,16,302)
  const float* ts      = (const float*)d_in[1];  // (3,50) flat
  const float* log_tau = (const float*)d_in[2];  // (16,)
  const float* sldj    = (const float*)d_in[3];  // scalar
  float* out = (float*)d_out;                    // 16*128*16*306 + 1
  float* ws  = (float*)d_ws;

  hipLaunchKernelGGL(build_kernel, dim3(48), dim3(256), 0, stream, ts, log_tau, ws);
  hipLaunchKernelGGL(apply_kernel, dim3(1536), dim3(256), 0, stream, z, ws, out);
  hipLaunchKernelGGL(finalize_kernel, dim3(1), dim3(64), 0, stream,
                     ws + PART_OFF, sldj, out, out_size - 1);
}

// Round 2
// 307.439 us; speedup vs baseline: 4.4574x; 4.4574x over previous
//
#include <hip/hip_runtime.h>

#define NBS 256

// ws layout (float offsets)
#define LT0_OFF 0         // 16*50*64   = 51200
#define LT1_OFF 51200     // 16*100*112 = 179200
#define LT2_OFF 230400    // 16*150*160 = 384000
#define A0_OFF  614400    // 16*64*2  = 2048
#define A1_OFF  616448    // 16*112*2 = 3584
#define A2_OFF  620032    // 16*160*2 = 5120
#define PART_OFF 625152   // 48 partial ldj sums

__device__ __forceinline__ int tri_i(int p) { return (p * (p + 1)) >> 1; }

// Exact packed-triangle decode for e < ~2M: 8e+1 fits fp32-exact for our range
// (e <= 11324), sqrt error <= 1 ulp -> at most +-1 off, fixed branch-free.
__device__ __forceinline__ void tri_decode(int e, int& r, int& c) {
  r = (int)((sqrtf(8.0f * (float)e + 1.0f) - 1.0f) * 0.5f);
  if (tri_i(r + 1) <= e) ++r;
  if (tri_i(r) > e) --r;
  c = e - tri_i(r);
}

// ---------------------------------------------------------------------------
// Kernel A: per (j,d) build A_mu, Sigma, Cholesky (raw Schur form).
// 1024 threads; rank-1 updates row-mapped (wave=row stride 16, lane=col
// stride 64) -> no per-element decode, 1 barrier per k.
// ---------------------------------------------------------------------------
__global__ __launch_bounds__(1024) void build_kernel(const float* __restrict__ ts,
                                                     const float* __restrict__ log_tau,
                                                     float* __restrict__ ws)
{
  __shared__ float sS[11325];   // packed lower triangle, max m=150
  __shared__ float stj[152];
  __shared__ float sAmu[304];
  __shared__ float sKp[304];
  __shared__ float red[1024];

  const int j = blockIdx.x >> 4;
  const int d = blockIdx.x & 15;
  const int m = (j + 1) * 50;
  const int mp    = (j == 0) ? 64      : ((j == 1) ? 112     : 160);
  const int ltoff = (j == 0) ? LT0_OFF : ((j == 1) ? LT1_OFF : LT2_OFF);
  const int aoff  = (j == 0) ? A0_OFF  : ((j == 1) ? A1_OFF  : A2_OFF);
  const float tpsj = (j == 0) ? 10.0f : ((j == 1) ? 20.0f : 30.0f);
  const int tid  = threadIdx.x;
  const int lane = tid & 63;
  const int wid  = tid >> 6;        // 16 waves

  const float tau = expf(log_tau[d]);
  const float cc = 1.0f / (2.0f * tau * tau);

  for (int i = tid; i < m; i += 1024) stj[i] = ts[i];
  __syncthreads();

  // 2x2 K_EPEP inverse: K = [[1,k01],[k01,1]]
  const float k01 = expf(-tpsj * tpsj * cc);
  const float det = 1.0f - k01 * k01;
  const float i00 = 1.0f / det;
  const float i01 = -k01 / det;

  for (int p = tid; p < m; p += 1024) {
    float tp = stj[p];
    float kp0 = expf(-tp * tp * cc);          // vs t=0
    float dt = tp - tpsj;
    float kp1 = expf(-dt * dt * cc);          // vs t=TPS[j]
    sKp[p * 2 + 0] = kp0; sKp[p * 2 + 1] = kp1;
    sAmu[p * 2 + 0] = fmaf(kp0, i00, kp1 * i01);
    sAmu[p * 2 + 1] = fmaf(kp0, i01, kp1 * i00);
  }
  __syncthreads();

  // Sigma (packed lower triangle), exact sqrt decode (no while loops)
  const int tot = tri_i(m);
  for (int e = tid; e < tot; e += 1024) {
    int r, q;
    tri_decode(e, r, q);
    float dq = stj[r] - stj[q];
    float v = expf(-dq * dq * cc)
            - fmaf(sAmu[r * 2], sKp[q * 2], sAmu[r * 2 + 1] * sKp[q * 2 + 1]);
    if (r == q) v += 1e-4f;
    sS[e] = v;
  }
  __syncthreads();

  // Raw Schur-complement Cholesky: columns stay UNSCALED; diag holds d_k.
  // Step k writes only (i,q) with i,q>k; reads only column k -> 1 barrier/k.
  // Row-mapped: wave wid owns rows i = k+1+wid, +16,...; lane owns cols.
  for (int k = 0; k < m - 1; ++k) {
    const float inv = -1.0f / sS[tri_i(k) + k];
    for (int i = k + 1 + wid; i < m; i += 16) {
      const int base = tri_i(i);
      const float ci = sS[base + k] * inv;     // broadcast read per wave
      for (int q = k + 1 + lane; q <= i; q += 64) {
        sS[base + q] = fmaf(ci, sS[tri_i(q) + k], sS[base + q]);
      }
    }
    __syncthreads();
  }

  // ldj partial: sum 0.5*log(d_p)
  float part = 0.0f;
  for (int p = tid; p < m; p += 1024) part += 0.5f * logf(sS[tri_i(p) + p]);
  red[tid] = part;
  __syncthreads();
  for (int s = 512; s > 0; s >>= 1) {
    if (tid < s) red[tid] += red[tid + s];
    __syncthreads();
  }
  if (tid == 0) ws[PART_OFF + blockIdx.x] = red[0];

  // L^T write, zero-padded: LT[q][p] = L[p][q] = S[p][q]/sqrt(d_q) (p>q), sqrt(d_p) (p==q)
  float* LTg = ws + ltoff + d * (m * mp);
  for (int idx = tid; idx < m * mp; idx += 1024) {
    int q = idx / mp;
    int p = idx - q * mp;
    float v = 0.0f;
    if (p < m && p >= q) {
      float dq = sS[tri_i(q) + q];
      v = (p == q) ? sqrtf(dq) : sS[tri_i(p) + q] * rsqrtf(dq);
    }
    LTg[idx] = v;
  }
  // A_mu write, zero-padded to mp rows
  float* Ag = ws + aoff + d * (mp * 2);
  for (int idx = tid; idx < mp * 2; idx += 1024) {
    int p = idx >> 1;
    Ag[idx] = (p < m) ? sAmu[idx] : 0.0f;
  }
}

// ---------------------------------------------------------------------------
// Kernel B: z_hat = A_mu * z_EP + L * z_mid, 64 rows/block, lane=row,
// waves own p-groups of 16, L rows are wave-uniform scalar loads.
// ---------------------------------------------------------------------------
template <int M, int MP, int TOFF, int OOFF, int LTOFF, int AOFF>
__device__ __forceinline__ void apply_impl(const float* __restrict__ z,
                                           const float* __restrict__ ws,
                                           float* __restrict__ out,
                                           float* zsh, int blk)
{
  constexpr int W = M + 3;            // odd row stride -> conflict-free columns
  constexpr int G = MP / 16;          // p-groups
  constexpr int NGW = (G + 3) / 4;    // max groups per wave
  const int d = blk & 15;
  const int bs0 = (blk >> 4) * 64;
  const int tid = threadIdx.x;
  const int lane = tid & 63;
  const int w = __builtin_amdgcn_readfirstlane(tid >> 6);

  // stage rows: [zf, zl, z_mid(0..M-1)]
  const float* zbase = z + (size_t)(bs0 * 16 + d) * 302;
  for (int idx = tid; idx < 64 * (M + 2); idx += NBS) {
    int rr = idx / (M + 2);
    int c = idx - rr * (M + 2);
    int t = (c < 2) ? c : (TOFF + c - 2);
    zsh[rr * W + c] = zbase[(size_t)rr * 4832 + t];
  }
  __syncthreads();

  float acc[NGW][16];
  const float* Ad = ws + AOFF + d * (MP * 2);
  const float* Ld = ws + LTOFF + d * (M * MP);
  const float zf = zsh[lane * W + 0];
  const float zl = zsh[lane * W + 1];

#pragma unroll
  for (int gi = 0; gi < NGW; ++gi) {
    const int g = w + 4 * gi;
    if (g < G) {
      const int pbase = g * 16;
#pragma unroll
      for (int i = 0; i < 16; ++i)
        acc[gi][i] = fmaf(Ad[(pbase + i) * 2 + 0], zf, Ad[(pbase + i) * 2 + 1] * zl);
      const float* Lp = Ld + pbase;
      for (int q = 0; q < M; ++q) {
        const float zv = zsh[lane * W + 2 + q];
        const float* Lr = Lp + q * MP;   // wave-uniform -> s_load
#pragma unroll
        for (int i = 0; i < 16; ++i)
          acc[gi][i] = fmaf(Lr[i], zv, acc[gi][i]);
      }
    }
  }
  __syncthreads();

  // write z_hat back into the LDS tile (cols 2..M+1); zf/zl at cols 0,1 preserved
#pragma unroll
  for (int gi = 0; gi < NGW; ++gi) {
    const int g = w + 4 * gi;
    if (g < G) {
      const int pbase = g * 16;
#pragma unroll
      for (int i = 0; i < 16; ++i) {
        const int p = pbase + i;
        if (p < M) zsh[lane * W + 2 + p] = acc[gi][i];
      }
    }
  }
  __syncthreads();

  // coalesced store: out row segment = [zf, z_hat(0..M-1), zl]
  for (int idx = tid; idx < 64 * (M + 2); idx += NBS) {
    int rr = idx / (M + 2);
    int c = idx - rr * (M + 2);
    float v = (c == 0) ? zsh[rr * W]
            : ((c == M + 1) ? zsh[rr * W + 1] : zsh[rr * W + c + 1]);
    out[(size_t)((bs0 + rr) * 16 + d) * 306 + OOFF + c] = v;
  }
}

__global__ __launch_bounds__(256) void apply_kernel(const float* __restrict__ z,
                                                    const float* __restrict__ ws,
                                                    float* __restrict__ out)
{
  __shared__ float zsh[64 * 153];
  const int bid = blockIdx.x;
  if (bid < 512)       apply_impl<150, 160, 152, 154, LT2_OFF, A2_OFF>(z, ws, out, zsh, bid);
  else if (bid < 1024) apply_impl<100, 112,  52,  52, LT1_OFF, A1_OFF>(z, ws, out, zsh, bid - 512);
  else                 apply_impl< 50,  64,   2,   0, LT0_OFF, A0_OFF>(z, ws, out, zsh, bid - 1024);
}

// ---------------------------------------------------------------------------
// Kernel C: ldj = sldj_in + sum of 48 partials
// ---------------------------------------------------------------------------
__global__ void finalize_kernel(const float* __restrict__ ws_part,
                                const float* __restrict__ sldj,
                                float* __restrict__ out, int last)
{
  if (threadIdx.x == 0) {
    float s = sldj[0];
    for (int i = 0; i < 48; ++i) s += ws_part[i];
    out[last] = s;
  }
}

extern "C" void kernel_launch(void* const* d_in, const int* in_sizes, int n_in,
                              void* d_out, int out_size, void* d_ws, size_t ws_size,
                              hipStream_t stream)
{
  const float* z       = (const float*)d_in[0];  // (16,128,16,302)
  const float* ts      = (const float*)d_in[1];  // (3,50) flat
  const float* log_tau = (const float*)d_in[2];  // (16,)
  const float* sldj    = (const float*)d_in[3];  // scalar
  float* out = (float*)d_out;                    // 16*128*16*306 + 1
  float* ws  = (float*)d_ws;

  hipLaunchKernelGGL(build_kernel, dim3(48), dim3(1024), 0, stream, ts, log_tau, ws);
  hipLaunchKernelGGL(apply_kernel, dim3(1536), dim3(256), 0, stream, z, ws, out);
  hipLaunchKernelGGL(finalize_kernel, dim3(1), dim3(64), 0, stream,
                     ws + PART_OFF, sldj, out, out_size - 1);
}